// Round 1
// baseline (2717.439 us; speedup 1.0000x reference)
//
#include <hip/hip_runtime.h>

#define NROWS 16384
#define DIMIN 1024
#define DIMH  512
#define MEMN  8192
#define NSPLIT 8

// ---------- mm[j] = sum_k memory[j][k]^2 ----------
__global__ __launch_bounds__(256) void k_row_sumsq(const float* __restrict__ mem,
                                                   float* __restrict__ mm) {
    int wave = threadIdx.x >> 6, lane = threadIdx.x & 63;
    int row = blockIdx.x * 4 + wave;
    const float4* r = (const float4*)(mem + (size_t)row * DIMH);
    float4 a = r[2 * lane], b = r[2 * lane + 1];
    float s = a.x*a.x + a.y*a.y + a.z*a.z + a.w*a.w
            + b.x*b.x + b.y*b.y + b.z*b.z + b.w*b.w;
    #pragma unroll
    for (int off = 32; off; off >>= 1) s += __shfl_xor(s, off, 64);
    if (lane == 0) mm[row] = s;
}

// ---------- C[M,N] = A[M,K] @ B[N,K]^T + bias[N] ----------
// 256 threads, tile 128x128, BK=16, micro 8x8
template<int N, int K>
__global__ __launch_bounds__(256) void k_gemm_bias(const float* __restrict__ A,
                                                   const float* __restrict__ B,
                                                   const float* __restrict__ bias,
                                                   float* __restrict__ C) {
    __shared__ float As[16][128];
    __shared__ float Bs[16][128];
    const int t = threadIdx.x, tx = t & 15, ty = t >> 4;
    const int bm = blockIdx.x * 128, bn = blockIdx.y * 128;
    float acc[8][8] = {};
    for (int kc = 0; kc < K; kc += 16) {
        #pragma unroll
        for (int j = 0; j < 2; ++j) {
            int f4 = t + 256 * j;
            int row = f4 >> 2, kq = (f4 & 3) * 4;
            float4 v = *(const float4*)(A + (size_t)(bm + row) * K + kc + kq);
            As[kq + 0][row] = v.x; As[kq + 1][row] = v.y;
            As[kq + 2][row] = v.z; As[kq + 3][row] = v.w;
            float4 w = *(const float4*)(B + (size_t)(bn + row) * K + kc + kq);
            Bs[kq + 0][row] = w.x; Bs[kq + 1][row] = w.y;
            Bs[kq + 2][row] = w.z; Bs[kq + 3][row] = w.w;
        }
        __syncthreads();
        #pragma unroll
        for (int k = 0; k < 16; ++k) {
            float4 a0 = *(const float4*)&As[k][ty * 8];
            float4 a1 = *(const float4*)&As[k][ty * 8 + 4];
            float4 b0 = *(const float4*)&Bs[k][tx * 8];
            float4 b1 = *(const float4*)&Bs[k][tx * 8 + 4];
            float av[8] = {a0.x, a0.y, a0.z, a0.w, a1.x, a1.y, a1.z, a1.w};
            float bv[8] = {b0.x, b0.y, b0.z, b0.w, b1.x, b1.y, b1.z, b1.w};
            #pragma unroll
            for (int i = 0; i < 8; ++i)
                #pragma unroll
                for (int jj = 0; jj < 8; ++jj)
                    acc[i][jj] = fmaf(av[i], bv[jj], acc[i][jj]);
        }
        __syncthreads();
    }
    float bb[8];
    #pragma unroll
    for (int jj = 0; jj < 8; ++jj) bb[jj] = bias[bn + tx * 8 + jj];
    #pragma unroll
    for (int i = 0; i < 8; ++i) {
        size_t base = (size_t)(bm + ty * 8 + i) * N + bn + tx * 8;
        float4 o0 = make_float4(acc[i][0] + bb[0], acc[i][1] + bb[1],
                                acc[i][2] + bb[2], acc[i][3] + bb[3]);
        float4 o1 = make_float4(acc[i][4] + bb[4], acc[i][5] + bb[5],
                                acc[i][6] + bb[6], acc[i][7] + bb[7]);
        *(float4*)(C + base) = o0;
        *(float4*)(C + base + 4) = o1;
    }
}

// ---------- per-row argmin of (mm[n] - 2 * p_i . mem_n) over a column split ----------
// 128 threads, BM=64 rows, BN=128 cols/iter, BK=16, micro 8x8 (ty: 8 rows, tx: 8 cols)
__global__ __launch_bounds__(128) void k_argmin(const float* __restrict__ P,
                                                const float* __restrict__ Mem,
                                                const float* __restrict__ mm,
                                                float* __restrict__ cval,
                                                int* __restrict__ cidx) {
    __shared__ float As[16][64];
    __shared__ float Bs[16][128];
    const int t = threadIdx.x, tx = t & 15, ty = t >> 4;  // ty 0..7
    const int bm = blockIdx.x * 64;
    const int split = blockIdx.y;
    const int nbase = split * (MEMN / NSPLIT);
    float bestv[8];
    int besti[8];
    #pragma unroll
    for (int i = 0; i < 8; ++i) { bestv[i] = 3.4e38f; besti[i] = 0; }

    for (int it = 0; it < (MEMN / NSPLIT) / 128; ++it) {
        const int bn = nbase + it * 128;
        float acc[8][8] = {};
        for (int kc = 0; kc < DIMH; kc += 16) {
            #pragma unroll
            for (int j = 0; j < 2; ++j) {
                int f4 = t + 128 * j;
                int row = f4 >> 2, kq = (f4 & 3) * 4;
                float4 v = *(const float4*)(P + (size_t)(bm + row) * DIMH + kc + kq);
                As[kq + 0][row] = v.x; As[kq + 1][row] = v.y;
                As[kq + 2][row] = v.z; As[kq + 3][row] = v.w;
            }
            #pragma unroll
            for (int j = 0; j < 4; ++j) {
                int f4 = t + 128 * j;
                int row = f4 >> 2, kq = (f4 & 3) * 4;
                float4 v = *(const float4*)(Mem + (size_t)(bn + row) * DIMH + kc + kq);
                Bs[kq + 0][row] = v.x; Bs[kq + 1][row] = v.y;
                Bs[kq + 2][row] = v.z; Bs[kq + 3][row] = v.w;
            }
            __syncthreads();
            #pragma unroll
            for (int k = 0; k < 16; ++k) {
                float4 a0 = *(const float4*)&As[k][ty * 8];
                float4 a1 = *(const float4*)&As[k][ty * 8 + 4];
                float4 b0 = *(const float4*)&Bs[k][tx * 8];
                float4 b1 = *(const float4*)&Bs[k][tx * 8 + 4];
                float av[8] = {a0.x, a0.y, a0.z, a0.w, a1.x, a1.y, a1.z, a1.w};
                float bv[8] = {b0.x, b0.y, b0.z, b0.w, b1.x, b1.y, b1.z, b1.w};
                #pragma unroll
                for (int i = 0; i < 8; ++i)
                    #pragma unroll
                    for (int jj = 0; jj < 8; ++jj)
                        acc[i][jj] = fmaf(av[i], bv[jj], acc[i][jj]);
            }
            __syncthreads();
        }
        // score epilogue: ascending n within thread; strict '<' keeps first (lowest idx)
        #pragma unroll
        for (int jj = 0; jj < 8; ++jj) {
            int n = bn + tx * 8 + jj;
            float mmv = mm[n];
            #pragma unroll
            for (int i = 0; i < 8; ++i) {
                float s = mmv - 2.0f * acc[i][jj];
                if (s < bestv[i]) { bestv[i] = s; besti[i] = n; }
            }
        }
    }
    // reduce across tx (low 4 lane bits within each wave)
    #pragma unroll
    for (int off = 1; off < 16; off <<= 1) {
        #pragma unroll
        for (int i = 0; i < 8; ++i) {
            float ov = __shfl_xor(bestv[i], off, 64);
            int oi = __shfl_xor(besti[i], off, 64);
            if (ov < bestv[i] || (ov == bestv[i] && oi < besti[i])) {
                bestv[i] = ov; besti[i] = oi;
            }
        }
    }
    if (tx == 0) {
        #pragma unroll
        for (int i = 0; i < 8; ++i) {
            int row = bm + ty * 8 + i;
            cval[(size_t)row * NSPLIT + split] = bestv[i];
            cidx[(size_t)row * NSPLIT + split] = besti[i];
        }
    }
}

// ---------- merge split candidates, write best idx, gather closest into out0 ----------
__global__ __launch_bounds__(256) void k_merge_gather(const float* __restrict__ cval,
                                                      const int* __restrict__ cidx,
                                                      const float* __restrict__ Mem,
                                                      float* __restrict__ out0,
                                                      int* __restrict__ bidx) {
    int wave = threadIdx.x >> 6, lane = threadIdx.x & 63;
    int row = blockIdx.x * 4 + wave;
    float bv = cval[(size_t)row * NSPLIT];
    int bi = cidx[(size_t)row * NSPLIT];
    #pragma unroll
    for (int s = 1; s < NSPLIT; ++s) {
        float v = cval[(size_t)row * NSPLIT + s];
        int ii = cidx[(size_t)row * NSPLIT + s];
        if (v < bv || (v == bv && ii < bi)) { bv = v; bi = ii; }
    }
    if (lane == 0) bidx[row] = bi;
    const float4* src = (const float4*)(Mem + (size_t)bi * DIMH);
    float4* dst = (float4*)(out0 + (size_t)row * DIMH);
    dst[lane] = src[lane];
    dst[lane + 64] = src[lane + 64];
}

// ---------- upd = (p - memory[bidx]) @ W_upd^T + b_upd; out1[bidx] += 0.5*upd ----------
// 256 threads, tile 128x128, BK=16, micro 8x8
__global__ __launch_bounds__(256) void k_upd_scatter(const float* __restrict__ P,
                                                     const float* __restrict__ Mem,
                                                     const int* __restrict__ bidx,
                                                     const float* __restrict__ W,
                                                     const float* __restrict__ bias,
                                                     float* __restrict__ out1) {
    __shared__ float As[16][128];
    __shared__ float Bs[16][128];
    __shared__ int ridx[128];
    const int t = threadIdx.x, tx = t & 15, ty = t >> 4;
    const int bm = blockIdx.x * 128, bn = blockIdx.y * 128;
    if (t < 128) ridx[t] = bidx[bm + t];
    __syncthreads();
    float acc[8][8] = {};
    for (int kc = 0; kc < DIMH; kc += 16) {
        #pragma unroll
        for (int j = 0; j < 2; ++j) {
            int f4 = t + 256 * j;
            int row = f4 >> 2, kq = (f4 & 3) * 4;
            float4 v = *(const float4*)(P + (size_t)(bm + row) * DIMH + kc + kq);
            float4 m = *(const float4*)(Mem + (size_t)ridx[row] * DIMH + kc + kq);
            As[kq + 0][row] = v.x - m.x; As[kq + 1][row] = v.y - m.y;
            As[kq + 2][row] = v.z - m.z; As[kq + 3][row] = v.w - m.w;
            float4 w = *(const float4*)(W + (size_t)(bn + row) * DIMH + kc + kq);
            Bs[kq + 0][row] = w.x; Bs[kq + 1][row] = w.y;
            Bs[kq + 2][row] = w.z; Bs[kq + 3][row] = w.w;
        }
        __syncthreads();
        #pragma unroll
        for (int k = 0; k < 16; ++k) {
            float4 a0 = *(const float4*)&As[k][ty * 8];
            float4 a1 = *(const float4*)&As[k][ty * 8 + 4];
            float4 b0 = *(const float4*)&Bs[k][tx * 8];
            float4 b1 = *(const float4*)&Bs[k][tx * 8 + 4];
            float av[8] = {a0.x, a0.y, a0.z, a0.w, a1.x, a1.y, a1.z, a1.w};
            float bv[8] = {b0.x, b0.y, b0.z, b0.w, b1.x, b1.y, b1.z, b1.w};
            #pragma unroll
            for (int i = 0; i < 8; ++i)
                #pragma unroll
                for (int jj = 0; jj < 8; ++jj)
                    acc[i][jj] = fmaf(av[i], bv[jj], acc[i][jj]);
        }
        __syncthreads();
    }
    float bb[8];
    #pragma unroll
    for (int jj = 0; jj < 8; ++jj) bb[jj] = bias[bn + tx * 8 + jj];
    #pragma unroll
    for (int i = 0; i < 8; ++i) {
        int target = ridx[ty * 8 + i];
        float* dst = out1 + (size_t)target * DIMH + bn + tx * 8;
        #pragma unroll
        for (int jj = 0; jj < 8; ++jj)
            atomicAdd(dst + jj, 0.5f * (acc[i][jj] + bb[jj]));
    }
}

extern "C" void kernel_launch(void* const* d_in, const int* in_sizes, int n_in,
                              void* d_out, int out_size, void* d_ws, size_t ws_size,
                              hipStream_t stream) {
    const float* visual = (const float*)d_in[0];
    const float* memory = (const float*)d_in[1];
    const float* W_proj = (const float*)d_in[2];
    const float* b_proj = (const float*)d_in[3];
    const float* W_upd  = (const float*)d_in[4];
    const float* b_upd  = (const float*)d_in[5];
    float* out0 = (float*)d_out;                     // closest [16384, 512]
    float* out1 = out0 + (size_t)NROWS * DIMH;       // updated_memory [8192, 512]

    char* ws = (char*)d_ws;
    float* p    = (float*)ws;                                   // 16384*512 f32
    float* mm   = (float*)(ws + (size_t)NROWS * DIMH * 4);      // 8192 f32
    float* cval = mm + MEMN;                                    // 16384*NSPLIT f32
    int*   cidx = (int*)(cval + (size_t)NROWS * NSPLIT);        // 16384*NSPLIT i32
    int*   bidx = cidx + (size_t)NROWS * NSPLIT;                // 16384 i32

    k_row_sumsq<<<MEMN / 4, 256, 0, stream>>>(memory, mm);
    k_gemm_bias<DIMH, DIMIN><<<dim3(NROWS / 128, DIMH / 128), 256, 0, stream>>>(
        visual, W_proj, b_proj, p);
    k_argmin<<<dim3(NROWS / 64, NSPLIT), 128, 0, stream>>>(p, memory, mm, cval, cidx);
    k_merge_gather<<<NROWS / 4, 256, 0, stream>>>(cval, cidx, memory, out0, bidx);
    hipMemcpyAsync(out1, memory, (size_t)MEMN * DIMH * 4, hipMemcpyDeviceToDevice, stream);
    k_upd_scatter<<<dim3(NROWS / 128, DIMH / 128), 256, 0, stream>>>(
        p, memory, bidx, W_upd, b_upd, out1);
}

// Round 2
// 1619.092 us; speedup vs baseline: 1.6784x; 1.6784x over previous
//
#include <hip/hip_runtime.h>

#define NROWS 16384
#define DIMIN 1024
#define DIMH  512
#define MEMN  8192
#define NSPLIT 8
#define CSLOTS (NSPLIT * 2)
#define TAU 0.05f

typedef __attribute__((ext_vector_type(8))) short bf16x8;
typedef __attribute__((ext_vector_type(4))) float f32x4;

__device__ __forceinline__ unsigned short bf16_rne(float x) {
    unsigned u = __builtin_bit_cast(unsigned, x);
    unsigned r = u + 0x7fffu + ((u >> 16) & 1u);
    return (unsigned short)(r >> 16);
}
__device__ __forceinline__ float bf16_to_f(unsigned short h) {
    unsigned u = ((unsigned)h) << 16;
    return __builtin_bit_cast(float, u);
}
__device__ __forceinline__ void async_copy16(const void* g, void* l) {
    __builtin_amdgcn_global_load_lds(
        (const __attribute__((address_space(1))) unsigned int*)g,
        (__attribute__((address_space(3))) unsigned int*)l, 16, 0, 0);
}

// ---------- mm[j] = sum memory[j]^2 ; split memory into bf16 hi/lo ----------
__global__ __launch_bounds__(256) void k_sumsq_split(const float* __restrict__ mem,
                                                     float* __restrict__ mm,
                                                     unsigned short* __restrict__ Mh,
                                                     unsigned short* __restrict__ Ml) {
    int wave = threadIdx.x >> 6, lane = threadIdx.x & 63;
    int row = blockIdx.x * 4 + wave;
    const float4* r4 = (const float4*)(mem + (size_t)row * DIMH);
    float4 a = r4[2 * lane], b = r4[2 * lane + 1];
    float x[8] = {a.x, a.y, a.z, a.w, b.x, b.y, b.z, b.w};
    union { unsigned short us[8]; int4 v; } hv, lv;
    float s = 0.f;
    #pragma unroll
    for (int i = 0; i < 8; ++i) {
        s = fmaf(x[i], x[i], s);
        unsigned short h = bf16_rne(x[i]);
        hv.us[i] = h;
        lv.us[i] = bf16_rne(x[i] - bf16_to_f(h));
    }
    #pragma unroll
    for (int off = 32; off; off >>= 1) s += __shfl_xor(s, off, 64);
    *(int4*)(Mh + (size_t)row * DIMH + lane * 8) = hv.v;
    *(int4*)(Ml + (size_t)row * DIMH + lane * 8) = lv.v;
    if (lane == 0) mm[row] = s;
}

// ---------- p = visual @ W_proj^T + b_proj, emitted as bf16 hi/lo split ----------
__global__ __launch_bounds__(256) void k_proj_split(const float* __restrict__ A,
                                                    const float* __restrict__ B,
                                                    const float* __restrict__ bias,
                                                    unsigned short* __restrict__ Ph,
                                                    unsigned short* __restrict__ Pl) {
    __shared__ float As[16][128];
    __shared__ float Bs[16][128];
    const int t = threadIdx.x, tx = t & 15, ty = t >> 4;
    const int bm = blockIdx.x * 128, bn = blockIdx.y * 128;
    float acc[8][8] = {};
    for (int kc = 0; kc < DIMIN; kc += 16) {
        #pragma unroll
        for (int j = 0; j < 2; ++j) {
            int f4 = t + 256 * j;
            int row = f4 >> 2, kq = (f4 & 3) * 4;
            float4 v = *(const float4*)(A + (size_t)(bm + row) * DIMIN + kc + kq);
            As[kq + 0][row] = v.x; As[kq + 1][row] = v.y;
            As[kq + 2][row] = v.z; As[kq + 3][row] = v.w;
            float4 w = *(const float4*)(B + (size_t)(bn + row) * DIMIN + kc + kq);
            Bs[kq + 0][row] = w.x; Bs[kq + 1][row] = w.y;
            Bs[kq + 2][row] = w.z; Bs[kq + 3][row] = w.w;
        }
        __syncthreads();
        #pragma unroll
        for (int k = 0; k < 16; ++k) {
            float4 a0 = *(const float4*)&As[k][ty * 8];
            float4 a1 = *(const float4*)&As[k][ty * 8 + 4];
            float4 b0 = *(const float4*)&Bs[k][tx * 8];
            float4 b1 = *(const float4*)&Bs[k][tx * 8 + 4];
            float av[8] = {a0.x, a0.y, a0.z, a0.w, a1.x, a1.y, a1.z, a1.w};
            float bv[8] = {b0.x, b0.y, b0.z, b0.w, b1.x, b1.y, b1.z, b1.w};
            #pragma unroll
            for (int i = 0; i < 8; ++i)
                #pragma unroll
                for (int jj = 0; jj < 8; ++jj)
                    acc[i][jj] = fmaf(av[i], bv[jj], acc[i][jj]);
        }
        __syncthreads();
    }
    float bb[8];
    #pragma unroll
    for (int jj = 0; jj < 8; ++jj) bb[jj] = bias[bn + tx * 8 + jj];
    #pragma unroll
    for (int i = 0; i < 8; ++i) {
        size_t base = (size_t)(bm + ty * 8 + i) * DIMH + bn + tx * 8;
        union { unsigned short us[8]; int4 v; } hv, lv;
        #pragma unroll
        for (int jj = 0; jj < 8; ++jj) {
            float o = acc[i][jj] + bb[jj];
            unsigned short h = bf16_rne(o);
            hv.us[jj] = h;
            lv.us[jj] = bf16_rne(o - bf16_to_f(h));
        }
        *(int4*)(Ph + base) = hv.v;
        *(int4*)(Pl + base) = lv.v;
    }
}

// ---------- MFMA split argmin: score = mm[n] - 2*(Ph+Pl).(Mh+Ml), track top-2 ----------
// 256 thr = 4 waves (2x2 over 128x128 tile), BK=32, 16x16x32 bf16 MFMA x3 products
__global__ __launch_bounds__(256, 2) void k_argmin_mfma(
        const unsigned short* __restrict__ Ph, const unsigned short* __restrict__ Pl,
        const unsigned short* __restrict__ Mh, const unsigned short* __restrict__ Ml,
        const float* __restrict__ mm,
        float* __restrict__ cval, int* __restrict__ cidx, float* __restrict__ cv2) {
    __shared__ unsigned short sAh[128 * 32];
    __shared__ unsigned short sAl[128 * 32];
    __shared__ unsigned short sBh[128 * 32];
    __shared__ unsigned short sBl[128 * 32];
    const int t = threadIdx.x;
    const int w = t >> 6, l = t & 63;
    const int wm = w >> 1, wn = w & 1;
    const int lane16 = l & 15, quad = l >> 4;
    const int bm = blockIdx.x * 128;
    const int split = blockIdx.y;
    const int nbase = split * (MEMN / NSPLIT);

    float bestv[16], bestv2[16];
    int besti[16];
    #pragma unroll
    for (int s = 0; s < 16; ++s) { bestv[s] = 3.4e38f; bestv2[s] = 3.4e38f; besti[s] = 0; }

    // staging coords (constant per thread): chunk c = t + 256*j covers row c/4, k (c&3)*8
    const int r0 = t >> 2, k0 = (t & 3) * 8;          // j = 0
    const int r1 = (t + 256) >> 2, k1 = (t & 3) * 8;  // j = 1
    const int lds0 = t * 8, lds1 = t * 8 + 2048;      // short offsets

    for (int it = 0; it < (MEMN / NSPLIT) / 128; ++it) {
        const int ntile = nbase + it * 128;
        f32x4 acc[4][4];
        #pragma unroll
        for (int mf = 0; mf < 4; ++mf)
            #pragma unroll
            for (int nf = 0; nf < 4; ++nf)
                acc[mf][nf] = (f32x4){0.f, 0.f, 0.f, 0.f};

        for (int kc = 0; kc < DIMH; kc += 32) {
            async_copy16(Ph + (size_t)(bm + r0) * DIMH + kc + k0, sAh + lds0);
            async_copy16(Ph + (size_t)(bm + r1) * DIMH + kc + k1, sAh + lds1);
            async_copy16(Pl + (size_t)(bm + r0) * DIMH + kc + k0, sAl + lds0);
            async_copy16(Pl + (size_t)(bm + r1) * DIMH + kc + k1, sAl + lds1);
            async_copy16(Mh + (size_t)(ntile + r0) * DIMH + kc + k0, sBh + lds0);
            async_copy16(Mh + (size_t)(ntile + r1) * DIMH + kc + k1, sBh + lds1);
            async_copy16(Ml + (size_t)(ntile + r0) * DIMH + kc + k0, sBl + lds0);
            async_copy16(Ml + (size_t)(ntile + r1) * DIMH + kc + k1, sBl + lds1);
            __syncthreads();

            bf16x8 ah[4], al[4];
            #pragma unroll
            for (int mf = 0; mf < 4; ++mf) {
                int r = wm * 64 + mf * 16 + lane16;
                ah[mf] = *(const bf16x8*)(sAh + r * 32 + quad * 8);
                al[mf] = *(const bf16x8*)(sAl + r * 32 + quad * 8);
            }
            #pragma unroll
            for (int nf = 0; nf < 4; ++nf) {
                int r = wn * 64 + nf * 16 + lane16;
                bf16x8 bh = *(const bf16x8*)(sBh + r * 32 + quad * 8);
                bf16x8 bl = *(const bf16x8*)(sBl + r * 32 + quad * 8);
                #pragma unroll
                for (int mf = 0; mf < 4; ++mf) {
                    acc[mf][nf] = __builtin_amdgcn_mfma_f32_16x16x32_bf16(ah[mf], bh, acc[mf][nf], 0, 0, 0);
                    acc[mf][nf] = __builtin_amdgcn_mfma_f32_16x16x32_bf16(ah[mf], bl, acc[mf][nf], 0, 0, 0);
                    acc[mf][nf] = __builtin_amdgcn_mfma_f32_16x16x32_bf16(al[mf], bh, acc[mf][nf], 0, 0, 0);
                }
            }
            __syncthreads();
        }
        // epilogue: C/D layout col=lane16 (n), row=quad*4+reg (m)
        #pragma unroll
        for (int nf = 0; nf < 4; ++nf) {
            int n = ntile + wn * 64 + nf * 16 + lane16;
            float mmv = mm[n];
            #pragma unroll
            for (int mf = 0; mf < 4; ++mf)
                #pragma unroll
                for (int r = 0; r < 4; ++r) {
                    float s = fmaf(-2.0f, acc[mf][nf][r], mmv);
                    int slot = mf * 4 + r;
                    if (s < bestv[slot]) {
                        bestv2[slot] = bestv[slot];
                        bestv[slot] = s; besti[slot] = n;
                    } else {
                        bestv2[slot] = fminf(bestv2[slot], s);
                    }
                }
        }
    }
    // reduce across the 16 column lanes (xor on lane16 bits keeps quad)
    #pragma unroll
    for (int off = 1; off < 16; off <<= 1) {
        #pragma unroll
        for (int s = 0; s < 16; ++s) {
            float ov = __shfl_xor(bestv[s], off, 64);
            int   oi = __shfl_xor(besti[s], off, 64);
            float o2 = __shfl_xor(bestv2[s], off, 64);
            bool take = (ov < bestv[s]) || (ov == bestv[s] && oi < besti[s]);
            float loser = take ? bestv[s] : ov;
            bestv2[s] = fminf(fminf(bestv2[s], o2), loser);
            if (take) { bestv[s] = ov; besti[s] = oi; }
        }
    }
    if (lane16 == 0) {
        #pragma unroll
        for (int mf = 0; mf < 4; ++mf)
            #pragma unroll
            for (int r = 0; r < 4; ++r) {
                int row = bm + wm * 64 + mf * 16 + quad * 4 + r;
                int slot = split * 2 + wn;
                cval[(size_t)row * CSLOTS + slot] = bestv[mf * 4 + r];
                cidx[(size_t)row * CSLOTS + slot] = besti[mf * 4 + r];
                cv2[(size_t)row * CSLOTS + slot] = bestv2[mf * 4 + r];
            }
    }
}

// ---------- merge split candidates; flag ambiguous rows; gather closest ----------
__global__ __launch_bounds__(256) void k_merge_gather(const float* __restrict__ cval,
                                                      const int* __restrict__ cidx,
                                                      const float* __restrict__ cv2,
                                                      const float* __restrict__ Mem,
                                                      float* __restrict__ out0,
                                                      int* __restrict__ bidx,
                                                      int* __restrict__ count,
                                                      int* __restrict__ list) {
    int wave = threadIdx.x >> 6, lane = threadIdx.x & 63;
    int row = blockIdx.x * 4 + wave;
    float v1 = 3.4e38f, v2 = 3.4e38f;
    int i1 = 0;
    #pragma unroll
    for (int s = 0; s < CSLOTS; ++s) {
        float a1 = cval[(size_t)row * CSLOTS + s];
        float a2 = cv2[(size_t)row * CSLOTS + s];
        int   ai = cidx[(size_t)row * CSLOTS + s];
        bool take = (a1 < v1) || (a1 == v1 && ai < i1);
        float loser = take ? v1 : a1;
        v2 = fminf(fminf(v2, a2), loser);
        if (take) { v1 = a1; i1 = ai; }
    }
    if (lane == 0) {
        bidx[row] = i1;
        if (v2 - v1 < TAU) {
            int pos = atomicAdd(count, 1);
            list[pos] = row;
        }
    }
    const float4* src = (const float4*)(Mem + (size_t)i1 * DIMH);
    float4* dst = (float4*)(out0 + (size_t)row * DIMH);
    dst[lane] = src[lane];
    dst[lane + 64] = src[lane + 64];
}

// ---------- exact fp32 re-decision for flagged rows ----------
__global__ __launch_bounds__(256) void k_rescan(const float* __restrict__ visual,
                                                const float* __restrict__ Wp,
                                                const float* __restrict__ bp,
                                                const float* __restrict__ Mem,
                                                const float* __restrict__ mm,
                                                const int* __restrict__ count,
                                                const int* __restrict__ list,
                                                int* __restrict__ bidx,
                                                float* __restrict__ out0) {
    __shared__ float p[DIMH];
    __shared__ float rv[256];
    __shared__ int ri[256];
    const int t = threadIdx.x;
    int cnt = *count;
    if (cnt > NROWS) cnt = NROWS;
    for (int f = blockIdx.x; f < cnt; f += gridDim.x) {
        int row = list[f];
        __syncthreads();
        for (int c = t; c < DIMH; c += 256) {
            float acc = bp[c];
            const float* vr = visual + (size_t)row * DIMIN;
            const float* wr = Wp + (size_t)c * DIMIN;
            for (int k = 0; k < DIMIN; k += 4) {
                acc = fmaf(vr[k + 0], wr[k + 0], acc);
                acc = fmaf(vr[k + 1], wr[k + 1], acc);
                acc = fmaf(vr[k + 2], wr[k + 2], acc);
                acc = fmaf(vr[k + 3], wr[k + 3], acc);
            }
            p[c] = acc;
        }
        __syncthreads();
        float bv = 3.4e38f; int bi = 0;
        for (int n = t; n < MEMN; n += 256) {
            const float* mr = Mem + (size_t)n * DIMH;
            float d = 0.f;
            for (int k = 0; k < DIMH; ++k) d = fmaf(p[k], mr[k], d);
            float s = fmaf(-2.f, d, mm[n]);
            if (s < bv) { bv = s; bi = n; }
        }
        rv[t] = bv; ri[t] = bi;
        __syncthreads();
        for (int off = 128; off; off >>= 1) {
            if (t < off) {
                float ov = rv[t + off]; int oi = ri[t + off];
                if (ov < rv[t] || (ov == rv[t] && oi < ri[t])) { rv[t] = ov; ri[t] = oi; }
            }
            __syncthreads();
        }
        int best = ri[0];
        if (t == 0) bidx[row] = best;
        for (int c = t; c < DIMH; c += 256)
            out0[(size_t)row * DIMH + c] = Mem[(size_t)best * DIMH + c];
    }
}

// ---------- upd = ((Ph+Pl) - memory[bidx]) @ W_upd^T + b_upd; out1[bidx] += 0.5*upd ----------
__global__ __launch_bounds__(256) void k_upd_scatter(const unsigned short* __restrict__ Ph,
                                                     const unsigned short* __restrict__ Pl,
                                                     const float* __restrict__ Mem,
                                                     const int* __restrict__ bidx,
                                                     const float* __restrict__ W,
                                                     const float* __restrict__ bias,
                                                     float* __restrict__ out1) {
    __shared__ float As[16][128];
    __shared__ float Bs[16][128];
    __shared__ int ridx[128];
    const int t = threadIdx.x, tx = t & 15, ty = t >> 4;
    const int bm = blockIdx.x * 128, bn = blockIdx.y * 128;
    if (t < 128) ridx[t] = bidx[bm + t];
    __syncthreads();
    float acc[8][8] = {};
    for (int kc = 0; kc < DIMH; kc += 16) {
        {
            int row = t >> 1, kq = (t & 1) * 8;
            union { unsigned short us[8]; int4 v; } hv, lv;
            hv.v = *(const int4*)(Ph + (size_t)(bm + row) * DIMH + kc + kq);
            lv.v = *(const int4*)(Pl + (size_t)(bm + row) * DIMH + kc + kq);
            const float4* mr = (const float4*)(Mem + (size_t)ridx[row] * DIMH + kc + kq);
            float4 m0 = mr[0], m1 = mr[1];
            float mv[8] = {m0.x, m0.y, m0.z, m0.w, m1.x, m1.y, m1.z, m1.w};
            #pragma unroll
            for (int i = 0; i < 8; ++i)
                As[kq + i][row] = bf16_to_f(hv.us[i]) + bf16_to_f(lv.us[i]) - mv[i];
            #pragma unroll
            for (int j = 0; j < 2; ++j) {
                int f4 = t + 256 * j;
                int row2 = f4 >> 2, kq2 = (f4 & 3) * 4;
                float4 w4 = *(const float4*)(W + (size_t)(bn + row2) * DIMH + kc + kq2);
                Bs[kq2 + 0][row2] = w4.x; Bs[kq2 + 1][row2] = w4.y;
                Bs[kq2 + 2][row2] = w4.z; Bs[kq2 + 3][row2] = w4.w;
            }
        }
        __syncthreads();
        #pragma unroll
        for (int k = 0; k < 16; ++k) {
            float4 a0 = *(const float4*)&As[k][ty * 8];
            float4 a1 = *(const float4*)&As[k][ty * 8 + 4];
            float4 b0 = *(const float4*)&Bs[k][tx * 8];
            float4 b1 = *(const float4*)&Bs[k][tx * 8 + 4];
            float av[8] = {a0.x, a0.y, a0.z, a0.w, a1.x, a1.y, a1.z, a1.w};
            float bv[8] = {b0.x, b0.y, b0.z, b0.w, b1.x, b1.y, b1.z, b1.w};
            #pragma unroll
            for (int i = 0; i < 8; ++i)
                #pragma unroll
                for (int jj = 0; jj < 8; ++jj)
                    acc[i][jj] = fmaf(av[i], bv[jj], acc[i][jj]);
        }
        __syncthreads();
    }
    float bb[8];
    #pragma unroll
    for (int jj = 0; jj < 8; ++jj) bb[jj] = bias[bn + tx * 8 + jj];
    #pragma unroll
    for (int i = 0; i < 8; ++i) {
        int target = ridx[ty * 8 + i];
        float* dst = out1 + (size_t)target * DIMH + bn + tx * 8;
        #pragma unroll
        for (int jj = 0; jj < 8; ++jj)
            atomicAdd(dst + jj, 0.5f * (acc[i][jj] + bb[jj]));
    }
}

extern "C" void kernel_launch(void* const* d_in, const int* in_sizes, int n_in,
                              void* d_out, int out_size, void* d_ws, size_t ws_size,
                              hipStream_t stream) {
    const float* visual = (const float*)d_in[0];
    const float* memory = (const float*)d_in[1];
    const float* W_proj = (const float*)d_in[2];
    const float* b_proj = (const float*)d_in[3];
    const float* W_upd  = (const float*)d_in[4];
    const float* b_upd  = (const float*)d_in[5];
    float* out0 = (float*)d_out;                     // closest [16384, 512]
    float* out1 = out0 + (size_t)NROWS * DIMH;       // updated_memory [8192, 512]

    char* ws = (char*)d_ws;
    unsigned short* Ph = (unsigned short*)ws;                  // 16 MB
    unsigned short* Pl = Ph + (size_t)NROWS * DIMH;            // 16 MB
    unsigned short* Mh = Pl + (size_t)NROWS * DIMH;            // 8 MB
    unsigned short* Ml = Mh + (size_t)MEMN * DIMH;             // 8 MB
    float* mm   = (float*)(Ml + (size_t)MEMN * DIMH);          // 32 KB
    float* cval = mm + MEMN;                                   // 1 MB
    float* cv2  = cval + (size_t)NROWS * CSLOTS;               // 1 MB
    int*   cidx = (int*)(cv2 + (size_t)NROWS * CSLOTS);        // 1 MB
    int*   bidx = cidx + (size_t)NROWS * CSLOTS;               // 64 KB
    int*   list = bidx + NROWS;                                // 64 KB
    int*   count = list + NROWS;                               // 4 B

    k_sumsq_split<<<MEMN / 4, 256, 0, stream>>>(memory, mm, Mh, Ml);
    k_proj_split<<<dim3(NROWS / 128, DIMH / 128), 256, 0, stream>>>(
        visual, W_proj, b_proj, Ph, Pl);
    k_argmin_mfma<<<dim3(NROWS / 128, NSPLIT), 256, 0, stream>>>(
        Ph, Pl, Mh, Ml, mm, cval, cidx, cv2);
    hipMemsetAsync(count, 0, 4, stream);
    k_merge_gather<<<NROWS / 4, 256, 0, stream>>>(
        cval, cidx, cv2, memory, out0, bidx, count, list);
    k_rescan<<<128, 256, 0, stream>>>(
        visual, W_proj, b_proj, memory, mm, count, list, bidx, out0);
    hipMemcpyAsync(out1, memory, (size_t)MEMN * DIMH * 4, hipMemcpyDeviceToDevice, stream);
    k_upd_scatter<<<dim3(NROWS / 128, DIMH / 128), 256, 0, stream>>>(
        Ph, Pl, memory, bidx, W_upd, b_upd, out1);
}

// Round 3
// 1002.101 us; speedup vs baseline: 2.7117x; 1.6157x over previous
//
#include <hip/hip_runtime.h>

#define NROWS 16384
#define DIMIN 1024
#define DIMH  512
#define MEMN  8192
#define NSPLIT 8
#define CSLOTS 16
#define TAU 0.05f

typedef __attribute__((ext_vector_type(8))) short bf16x8;
typedef __attribute__((ext_vector_type(4))) float f32x4;

__device__ __forceinline__ unsigned short bf16_rne(float x) {
    unsigned u = __builtin_bit_cast(unsigned, x);
    unsigned r = u + 0x7fffu + ((u >> 16) & 1u);
    return (unsigned short)(r >> 16);
}
__device__ __forceinline__ float bf16_to_f(unsigned short h) {
    unsigned u = ((unsigned)h) << 16;
    return __builtin_bit_cast(float, u);
}
__device__ __forceinline__ void async_copy16(const void* g, void* l) {
    __builtin_amdgcn_global_load_lds(
        (const __attribute__((address_space(1))) unsigned int*)g,
        (__attribute__((address_space(3))) unsigned int*)l, 16, 0, 0);
}

// ---------- mm[j] = sum memory[j]^2 ; split memory into bf16 hi/lo ----------
__global__ __launch_bounds__(256) void k_sumsq_split(const float* __restrict__ mem,
                                                     float* __restrict__ mm,
                                                     unsigned short* __restrict__ Mh,
                                                     unsigned short* __restrict__ Ml) {
    int wave = threadIdx.x >> 6, lane = threadIdx.x & 63;
    int row = blockIdx.x * 4 + wave;
    const float4* r4 = (const float4*)(mem + (size_t)row * DIMH);
    float4 a = r4[2 * lane], b = r4[2 * lane + 1];
    float x[8] = {a.x, a.y, a.z, a.w, b.x, b.y, b.z, b.w};
    union { unsigned short us[8]; int4 v; } hv, lv;
    float s = 0.f;
    #pragma unroll
    for (int i = 0; i < 8; ++i) {
        s = fmaf(x[i], x[i], s);
        unsigned short h = bf16_rne(x[i]);
        hv.us[i] = h;
        lv.us[i] = bf16_rne(x[i] - bf16_to_f(h));
    }
    #pragma unroll
    for (int off = 32; off; off >>= 1) s += __shfl_xor(s, off, 64);
    *(int4*)(Mh + (size_t)row * DIMH + lane * 8) = hv.v;
    *(int4*)(Ml + (size_t)row * DIMH + lane * 8) = lv.v;
    if (lane == 0) mm[row] = s;
}

// ---------- generic fp32 -> bf16 hi/lo splitter (8 elems/thread) ----------
__global__ __launch_bounds__(256) void k_split(const float* __restrict__ x,
                                               unsigned short* __restrict__ h,
                                               unsigned short* __restrict__ l, int n) {
    int i = (blockIdx.x * 256 + threadIdx.x) * 8;
    if (i >= n) return;
    const float4* xp = (const float4*)(x + i);
    float4 a = xp[0], b = xp[1];
    float v[8] = {a.x, a.y, a.z, a.w, b.x, b.y, b.z, b.w};
    union { unsigned short us[8]; int4 q; } hv, lv;
    #pragma unroll
    for (int j = 0; j < 8; ++j) {
        unsigned short hh = bf16_rne(v[j]);
        hv.us[j] = hh;
        lv.us[j] = bf16_rne(v[j] - bf16_to_f(hh));
    }
    *(int4*)(h + i) = hv.q;
    *(int4*)(l + i) = lv.q;
}

// ---------- p = visual @ Wp^T + b : split-bf16 MFMA, output split Ph/Pl ----------
// A fp32 staged + split in-reg; B pre-split bf16 via async LDS. 128x128 tile, BK=32.
__global__ __launch_bounds__(256, 2) void k_proj_mfma(
        const float* __restrict__ A,
        const unsigned short* __restrict__ Bh, const unsigned short* __restrict__ Bl,
        const float* __restrict__ bias,
        unsigned short* __restrict__ Ph, unsigned short* __restrict__ Pl) {
    __shared__ unsigned short sAh[128 * 32];
    __shared__ unsigned short sAl[128 * 32];
    __shared__ unsigned short sBh[128 * 32];
    __shared__ unsigned short sBl[128 * 32];
    const int t = threadIdx.x, w = t >> 6, l = t & 63;
    const int wm = w >> 1, wn = w & 1, lane16 = l & 15, quad = l >> 4;
    const int bm = blockIdx.x * 128, bn = blockIdx.y * 128;
    const int r0 = t >> 2, k0 = (t & 3) * 8, r1 = (t + 256) >> 2;
    const int lds0 = t * 8, lds1 = t * 8 + 2048;
    const int ar = t >> 1, ak = (t & 1) * 16;

    f32x4 acc[4][4];
    #pragma unroll
    for (int mf = 0; mf < 4; ++mf)
        #pragma unroll
        for (int nf = 0; nf < 4; ++nf) acc[mf][nf] = (f32x4){0.f, 0.f, 0.f, 0.f};

    for (int kc = 0; kc < DIMIN; kc += 32) {
        async_copy16(Bh + (size_t)(bn + r0) * DIMIN + kc + k0, sBh + lds0);
        async_copy16(Bh + (size_t)(bn + r1) * DIMIN + kc + k0, sBh + lds1);
        async_copy16(Bl + (size_t)(bn + r0) * DIMIN + kc + k0, sBl + lds0);
        async_copy16(Bl + (size_t)(bn + r1) * DIMIN + kc + k0, sBl + lds1);
        {
            const float4* ap = (const float4*)(A + (size_t)(bm + ar) * DIMIN + kc + ak);
            float4 v0 = ap[0], v1 = ap[1], v2 = ap[2], v3 = ap[3];
            float x[16] = {v0.x, v0.y, v0.z, v0.w, v1.x, v1.y, v1.z, v1.w,
                           v2.x, v2.y, v2.z, v2.w, v3.x, v3.y, v3.z, v3.w};
            union { unsigned short us[16]; int4 q[2]; } hv, lv;
            #pragma unroll
            for (int j = 0; j < 16; ++j) {
                unsigned short hh = bf16_rne(x[j]);
                hv.us[j] = hh;
                lv.us[j] = bf16_rne(x[j] - bf16_to_f(hh));
            }
            *(int4*)(sAh + ar * 32 + ak) = hv.q[0];
            *(int4*)(sAh + ar * 32 + ak + 8) = hv.q[1];
            *(int4*)(sAl + ar * 32 + ak) = lv.q[0];
            *(int4*)(sAl + ar * 32 + ak + 8) = lv.q[1];
        }
        __syncthreads();
        bf16x8 ah[4], al[4];
        #pragma unroll
        for (int mf = 0; mf < 4; ++mf) {
            int r = wm * 64 + mf * 16 + lane16;
            ah[mf] = *(const bf16x8*)(sAh + r * 32 + quad * 8);
            al[mf] = *(const bf16x8*)(sAl + r * 32 + quad * 8);
        }
        #pragma unroll
        for (int nf = 0; nf < 4; ++nf) {
            int r = wn * 64 + nf * 16 + lane16;
            bf16x8 bh = *(const bf16x8*)(sBh + r * 32 + quad * 8);
            bf16x8 bl = *(const bf16x8*)(sBl + r * 32 + quad * 8);
            #pragma unroll
            for (int mf = 0; mf < 4; ++mf) {
                acc[mf][nf] = __builtin_amdgcn_mfma_f32_16x16x32_bf16(ah[mf], bh, acc[mf][nf], 0, 0, 0);
                acc[mf][nf] = __builtin_amdgcn_mfma_f32_16x16x32_bf16(ah[mf], bl, acc[mf][nf], 0, 0, 0);
                acc[mf][nf] = __builtin_amdgcn_mfma_f32_16x16x32_bf16(al[mf], bh, acc[mf][nf], 0, 0, 0);
            }
        }
        __syncthreads();
    }
    #pragma unroll
    for (int nf = 0; nf < 4; ++nf) {
        int col = bn + wn * 64 + nf * 16 + lane16;
        float bb = bias[col];
        #pragma unroll
        for (int mf = 0; mf < 4; ++mf)
            #pragma unroll
            for (int r = 0; r < 4; ++r) {
                int row = bm + wm * 64 + mf * 16 + quad * 4 + r;
                float o = acc[mf][nf][r] + bb;
                unsigned short hh = bf16_rne(o);
                unsigned short ll = bf16_rne(o - bf16_to_f(hh));
                Ph[(size_t)row * DIMH + col] = hh;
                Pl[(size_t)row * DIMH + col] = ll;
            }
    }
}

// ---------- MFMA split argmin with per-slot top-2 (values AND indices) ----------
__global__ __launch_bounds__(256, 2) void k_argmin_mfma(
        const unsigned short* __restrict__ Ph, const unsigned short* __restrict__ Pl,
        const unsigned short* __restrict__ Mh, const unsigned short* __restrict__ Ml,
        const float* __restrict__ mm,
        float* __restrict__ cval, int* __restrict__ cidx,
        float* __restrict__ cv2, int* __restrict__ cidx2) {
    __shared__ unsigned short sAh[128 * 32];
    __shared__ unsigned short sAl[128 * 32];
    __shared__ unsigned short sBh[128 * 32];
    __shared__ unsigned short sBl[128 * 32];
    const int t = threadIdx.x;
    const int w = t >> 6, l = t & 63;
    const int wm = w >> 1, wn = w & 1;
    const int lane16 = l & 15, quad = l >> 4;
    const int bm = blockIdx.x * 128;
    const int split = blockIdx.y;
    const int nbase = split * (MEMN / NSPLIT);

    float bestv[16], bestv2[16];
    int besti[16], besti2[16];
    #pragma unroll
    for (int s = 0; s < 16; ++s) {
        bestv[s] = 3.4e38f; bestv2[s] = 3.4e38f; besti[s] = 0; besti2[s] = 0;
    }

    const int r0 = t >> 2, k0 = (t & 3) * 8;
    const int r1 = (t + 256) >> 2, k1 = (t & 3) * 8;
    const int lds0 = t * 8, lds1 = t * 8 + 2048;

    for (int it = 0; it < (MEMN / NSPLIT) / 128; ++it) {
        const int ntile = nbase + it * 128;
        f32x4 acc[4][4];
        #pragma unroll
        for (int mf = 0; mf < 4; ++mf)
            #pragma unroll
            for (int nf = 0; nf < 4; ++nf) acc[mf][nf] = (f32x4){0.f, 0.f, 0.f, 0.f};

        for (int kc = 0; kc < DIMH; kc += 32) {
            async_copy16(Ph + (size_t)(bm + r0) * DIMH + kc + k0, sAh + lds0);
            async_copy16(Ph + (size_t)(bm + r1) * DIMH + kc + k1, sAh + lds1);
            async_copy16(Pl + (size_t)(bm + r0) * DIMH + kc + k0, sAl + lds0);
            async_copy16(Pl + (size_t)(bm + r1) * DIMH + kc + k1, sAl + lds1);
            async_copy16(Mh + (size_t)(ntile + r0) * DIMH + kc + k0, sBh + lds0);
            async_copy16(Mh + (size_t)(ntile + r1) * DIMH + kc + k1, sBh + lds1);
            async_copy16(Ml + (size_t)(ntile + r0) * DIMH + kc + k0, sBl + lds0);
            async_copy16(Ml + (size_t)(ntile + r1) * DIMH + kc + k1, sBl + lds1);
            __syncthreads();

            bf16x8 ah[4], al[4];
            #pragma unroll
            for (int mf = 0; mf < 4; ++mf) {
                int r = wm * 64 + mf * 16 + lane16;
                ah[mf] = *(const bf16x8*)(sAh + r * 32 + quad * 8);
                al[mf] = *(const bf16x8*)(sAl + r * 32 + quad * 8);
            }
            #pragma unroll
            for (int nf = 0; nf < 4; ++nf) {
                int r = wn * 64 + nf * 16 + lane16;
                bf16x8 bh = *(const bf16x8*)(sBh + r * 32 + quad * 8);
                bf16x8 bl = *(const bf16x8*)(sBl + r * 32 + quad * 8);
                #pragma unroll
                for (int mf = 0; mf < 4; ++mf) {
                    acc[mf][nf] = __builtin_amdgcn_mfma_f32_16x16x32_bf16(ah[mf], bh, acc[mf][nf], 0, 0, 0);
                    acc[mf][nf] = __builtin_amdgcn_mfma_f32_16x16x32_bf16(ah[mf], bl, acc[mf][nf], 0, 0, 0);
                    acc[mf][nf] = __builtin_amdgcn_mfma_f32_16x16x32_bf16(al[mf], bh, acc[mf][nf], 0, 0, 0);
                }
            }
            __syncthreads();
        }
        #pragma unroll
        for (int nf = 0; nf < 4; ++nf) {
            int n = ntile + wn * 64 + nf * 16 + lane16;
            float mmv = mm[n];
            #pragma unroll
            for (int mf = 0; mf < 4; ++mf)
                #pragma unroll
                for (int r = 0; r < 4; ++r) {
                    float s = fmaf(-2.0f, acc[mf][nf][r], mmv);
                    int slot = mf * 4 + r;
                    if (s < bestv[slot]) {
                        bestv2[slot] = bestv[slot]; besti2[slot] = besti[slot];
                        bestv[slot] = s; besti[slot] = n;
                    } else if (s < bestv2[slot]) {
                        bestv2[slot] = s; besti2[slot] = n;
                    }
                }
        }
    }
    // top-2 merge across the 16 column lanes
    #pragma unroll
    for (int off = 1; off < 16; off <<= 1) {
        #pragma unroll
        for (int s = 0; s < 16; ++s) {
            float ov = __shfl_xor(bestv[s], off, 64);
            int   oi = __shfl_xor(besti[s], off, 64);
            float o2 = __shfl_xor(bestv2[s], off, 64);
            int   oi2 = __shfl_xor(besti2[s], off, 64);
            if (ov < bestv[s] || (ov == bestv[s] && oi < besti[s])) {
                if (bestv[s] < o2 || (bestv[s] == o2 && besti[s] < oi2)) {
                    bestv2[s] = bestv[s]; besti2[s] = besti[s];
                } else {
                    bestv2[s] = o2; besti2[s] = oi2;
                }
                bestv[s] = ov; besti[s] = oi;
            } else {
                if (ov < bestv2[s] || (ov == bestv2[s] && oi < besti2[s])) {
                    bestv2[s] = ov; besti2[s] = oi;
                }
            }
        }
    }
    if (lane16 == 0) {
        #pragma unroll
        for (int mf = 0; mf < 4; ++mf)
            #pragma unroll
            for (int r = 0; r < 4; ++r) {
                int row = bm + wm * 64 + mf * 16 + quad * 4 + r;
                int slot = split * 2 + wn;
                size_t o = (size_t)row * CSLOTS + slot;
                cval[o] = bestv[mf * 4 + r];
                cidx[o] = besti[mf * 4 + r];
                cv2[o]  = bestv2[mf * 4 + r];
                cidx2[o] = besti2[mf * 4 + r];
            }
    }
}

// ---------- merge slots -> global best; flag rows with gap < TAU; gather ----------
__global__ __launch_bounds__(256) void k_merge_gather(const float* __restrict__ cval,
                                                      const int* __restrict__ cidx,
                                                      const float* __restrict__ cv2,
                                                      const float* __restrict__ Mem,
                                                      float* __restrict__ out0,
                                                      int* __restrict__ bidx,
                                                      int* __restrict__ count,
                                                      int* __restrict__ list) {
    int wave = threadIdx.x >> 6, lane = threadIdx.x & 63;
    int row = blockIdx.x * 4 + wave;
    float v1 = 3.4e38f, v2 = 3.4e38f;
    int i1 = 0;
    #pragma unroll
    for (int s = 0; s < CSLOTS; ++s) {
        float a1 = cval[(size_t)row * CSLOTS + s];
        float b2 = cv2[(size_t)row * CSLOTS + s];
        int   ai = cidx[(size_t)row * CSLOTS + s];
        if (a1 < v1 || (a1 == v1 && ai < i1)) {
            v2 = fminf(v1, b2);
            v1 = a1; i1 = ai;
        } else {
            v2 = fminf(v2, a1);
        }
    }
    if (lane == 0) {
        bidx[row] = i1;
        if (v2 - v1 < TAU) {
            int pos = atomicAdd(count, 1);
            list[pos] = row;
        }
    }
    const float4* src = (const float4*)(Mem + (size_t)i1 * DIMH);
    float4* dst = (float4*)(out0 + (size_t)row * DIMH);
    dst[lane] = src[lane];
    dst[lane + 64] = src[lane + 64];
}

// ---------- exact fp32 re-decision among the 32 slot candidates ----------
__global__ __launch_bounds__(256) void k_rescan(const float* __restrict__ visual,
                                                const float* __restrict__ Wp,
                                                const float* __restrict__ bp,
                                                const float* __restrict__ Mem,
                                                const float* __restrict__ mm,
                                                const int* __restrict__ count,
                                                const int* __restrict__ list,
                                                const int* __restrict__ cidx,
                                                const int* __restrict__ cidx2,
                                                int* __restrict__ bidx,
                                                float* __restrict__ out0) {
    __shared__ float vrow[DIMIN];
    __shared__ float p[DIMH];
    __shared__ float sv[32];
    __shared__ int   si[32];
    __shared__ int   sbest;
    const int t = threadIdx.x;
    int cnt = *count;
    if (cnt > NROWS) cnt = NROWS;
    for (int f = blockIdx.x; f < cnt; f += gridDim.x) {
        int row = list[f];
        __syncthreads();
        *(float4*)&vrow[t * 4] = *(const float4*)(visual + (size_t)row * DIMIN + t * 4);
        __syncthreads();
        // exact projection: 2 cols per thread
        #pragma unroll
        for (int cc = 0; cc < 2; ++cc) {
            int c = t + cc * 256;
            const float* wr = Wp + (size_t)c * DIMIN;
            float a0 = 0.f, a1 = 0.f, a2 = 0.f, a3 = 0.f;
            for (int k = 0; k < DIMIN; k += 16) {
                float4 w0 = *(const float4*)(wr + k);
                float4 w1 = *(const float4*)(wr + k + 4);
                float4 w2 = *(const float4*)(wr + k + 8);
                float4 w3 = *(const float4*)(wr + k + 12);
                float4 x0 = *(const float4*)&vrow[k];
                float4 x1 = *(const float4*)&vrow[k + 4];
                float4 x2 = *(const float4*)&vrow[k + 8];
                float4 x3 = *(const float4*)&vrow[k + 12];
                a0 = fmaf(w0.x, x0.x, fmaf(w0.y, x0.y, fmaf(w0.z, x0.z, fmaf(w0.w, x0.w, a0))));
                a1 = fmaf(w1.x, x1.x, fmaf(w1.y, x1.y, fmaf(w1.z, x1.z, fmaf(w1.w, x1.w, a1))));
                a2 = fmaf(w2.x, x2.x, fmaf(w2.y, x2.y, fmaf(w2.z, x2.z, fmaf(w2.w, x2.w, a2))));
                a3 = fmaf(w3.x, x3.x, fmaf(w3.y, x3.y, fmaf(w3.z, x3.z, fmaf(w3.w, x3.w, a3))));
            }
            p[c] = bp[c] + ((a0 + a1) + (a2 + a3));
        }
        __syncthreads();
        // 32 candidates x 8 threads each
        int g = t >> 3, sub = t & 7;
        int cand = (g < 16) ? cidx[(size_t)row * CSLOTS + g]
                            : cidx2[(size_t)row * CSLOTS + (g - 16)];
        const float* mr = Mem + (size_t)cand * DIMH + sub * 64;
        const float* pp = p + sub * 64;
        float d = 0.f;
        for (int k = 0; k < 64; k += 4) {
            float4 mv = *(const float4*)(mr + k);
            float4 pv = *(const float4*)(pp + k);
            d = fmaf(mv.x, pv.x, fmaf(mv.y, pv.y, fmaf(mv.z, pv.z, fmaf(mv.w, pv.w, d))));
        }
        #pragma unroll
        for (int off = 1; off < 8; off <<= 1) d += __shfl_xor(d, off, 64);
        if (sub == 0) {
            sv[g] = fmaf(-2.f, d, mm[cand]);
            si[g] = cand;
        }
        __syncthreads();
        if (t == 0) {
            float bv = sv[0]; int bi = si[0];
            for (int gg = 1; gg < 32; ++gg) {
                float v = sv[gg]; int ii = si[gg];
                if (v < bv || (v == bv && ii < bi)) { bv = v; bi = ii; }
            }
            bidx[row] = bi;
            sbest = bi;
        }
        __syncthreads();
        int best = sbest;
        if (t < 128)
            *(float4*)(out0 + (size_t)row * DIMH + t * 4) =
                *(const float4*)(Mem + (size_t)best * DIMH + t * 4);
    }
}

// ---------- upd = ((Ph+Pl) - mem[bidx]) @ Wu^T + b; out1[bidx] += 0.5*upd ----------
// A computed + split in staging; B pre-split bf16 via async. 128x128 tile, BK=32.
__global__ __launch_bounds__(256, 2) void k_upd_mfma(
        const unsigned short* __restrict__ Ph, const unsigned short* __restrict__ Pl,
        const float* __restrict__ Mem, const int* __restrict__ bidx,
        const unsigned short* __restrict__ Bh, const unsigned short* __restrict__ Bl,
        const float* __restrict__ bias, float* __restrict__ out1) {
    __shared__ unsigned short sAh[128 * 32];
    __shared__ unsigned short sAl[128 * 32];
    __shared__ unsigned short sBh[128 * 32];
    __shared__ unsigned short sBl[128 * 32];
    __shared__ int ridx[128];
    const int t = threadIdx.x, w = t >> 6, l = t & 63;
    const int wm = w >> 1, wn = w & 1, lane16 = l & 15, quad = l >> 4;
    const int bm = blockIdx.x * 128, bn = blockIdx.y * 128;
    const int r0 = t >> 2, k0 = (t & 3) * 8, r1 = (t + 256) >> 2;
    const int lds0 = t * 8, lds1 = t * 8 + 2048;
    const int ar = t >> 1, ak = (t & 1) * 16;
    if (t < 128) ridx[t] = bidx[bm + t];
    __syncthreads();

    f32x4 acc[4][4];
    #pragma unroll
    for (int mf = 0; mf < 4; ++mf)
        #pragma unroll
        for (int nf = 0; nf < 4; ++nf) acc[mf][nf] = (f32x4){0.f, 0.f, 0.f, 0.f};

    for (int kc = 0; kc < DIMH; kc += 32) {
        async_copy16(Bh + (size_t)(bn + r0) * DIMH + kc + k0, sBh + lds0);
        async_copy16(Bh + (size_t)(bn + r1) * DIMH + kc + k0, sBh + lds1);
        async_copy16(Bl + (size_t)(bn + r0) * DIMH + kc + k0, sBl + lds0);
        async_copy16(Bl + (size_t)(bn + r1) * DIMH + kc + k0, sBl + lds1);
        {
            const unsigned short* ph = Ph + (size_t)(bm + ar) * DIMH + kc + ak;
            const unsigned short* pl = Pl + (size_t)(bm + ar) * DIMH + kc + ak;
            union { unsigned short us[16]; int4 q[2]; } hq, lq;
            hq.q[0] = *(const int4*)ph; hq.q[1] = *(const int4*)(ph + 8);
            lq.q[0] = *(const int4*)pl; lq.q[1] = *(const int4*)(pl + 8);
            const float* mrow = Mem + (size_t)ridx[ar] * DIMH + kc + ak;
            float4 m0 = *(const float4*)(mrow), m1 = *(const float4*)(mrow + 4);
            float4 m2 = *(const float4*)(mrow + 8), m3 = *(const float4*)(mrow + 12);
            float mv[16] = {m0.x, m0.y, m0.z, m0.w, m1.x, m1.y, m1.z, m1.w,
                            m2.x, m2.y, m2.z, m2.w, m3.x, m3.y, m3.z, m3.w};
            union { unsigned short us[16]; int4 q[2]; } hv, lv;
            #pragma unroll
            for (int j = 0; j < 16; ++j) {
                float d = bf16_to_f(hq.us[j]) + bf16_to_f(lq.us[j]) - mv[j];
                unsigned short hh = bf16_rne(d);
                hv.us[j] = hh;
                lv.us[j] = bf16_rne(d - bf16_to_f(hh));
            }
            *(int4*)(sAh + ar * 32 + ak) = hv.q[0];
            *(int4*)(sAh + ar * 32 + ak + 8) = hv.q[1];
            *(int4*)(sAl + ar * 32 + ak) = lv.q[0];
            *(int4*)(sAl + ar * 32 + ak + 8) = lv.q[1];
        }
        __syncthreads();
        bf16x8 ah[4], al[4];
        #pragma unroll
        for (int mf = 0; mf < 4; ++mf) {
            int r = wm * 64 + mf * 16 + lane16;
            ah[mf] = *(const bf16x8*)(sAh + r * 32 + quad * 8);
            al[mf] = *(const bf16x8*)(sAl + r * 32 + quad * 8);
        }
        #pragma unroll
        for (int nf = 0; nf < 4; ++nf) {
            int r = wn * 64 + nf * 16 + lane16;
            bf16x8 bh = *(const bf16x8*)(sBh + r * 32 + quad * 8);
            bf16x8 bl = *(const bf16x8*)(sBl + r * 32 + quad * 8);
            #pragma unroll
            for (int mf = 0; mf < 4; ++mf) {
                acc[mf][nf] = __builtin_amdgcn_mfma_f32_16x16x32_bf16(ah[mf], bh, acc[mf][nf], 0, 0, 0);
                acc[mf][nf] = __builtin_amdgcn_mfma_f32_16x16x32_bf16(ah[mf], bl, acc[mf][nf], 0, 0, 0);
                acc[mf][nf] = __builtin_amdgcn_mfma_f32_16x16x32_bf16(al[mf], bh, acc[mf][nf], 0, 0, 0);
            }
        }
        __syncthreads();
    }
    #pragma unroll
    for (int nf = 0; nf < 4; ++nf) {
        int col = bn + wn * 64 + nf * 16 + lane16;
        float bb = bias[col];
        #pragma unroll
        for (int mf = 0; mf < 4; ++mf)
            #pragma unroll
            for (int r = 0; r < 4; ++r) {
                int rowl = wm * 64 + mf * 16 + quad * 4 + r;
                int tgt = ridx[rowl];
                atomicAdd(out1 + (size_t)tgt * DIMH + col, 0.5f * (acc[mf][nf][r] + bb));
            }
    }
}

extern "C" void kernel_launch(void* const* d_in, const int* in_sizes, int n_in,
                              void* d_out, int out_size, void* d_ws, size_t ws_size,
                              hipStream_t stream) {
    const float* visual = (const float*)d_in[0];
    const float* memory = (const float*)d_in[1];
    const float* W_proj = (const float*)d_in[2];
    const float* b_proj = (const float*)d_in[3];
    const float* W_upd  = (const float*)d_in[4];
    const float* b_upd  = (const float*)d_in[5];
    float* out0 = (float*)d_out;
    float* out1 = out0 + (size_t)NROWS * DIMH;

    char* ws = (char*)d_ws;
    unsigned short* Ph  = (unsigned short*)ws;
    unsigned short* Pl  = Ph + (size_t)NROWS * DIMH;
    unsigned short* Mh  = Pl + (size_t)NROWS * DIMH;
    unsigned short* Ml  = Mh + (size_t)MEMN * DIMH;
    unsigned short* Wph = Ml + (size_t)MEMN * DIMH;
    unsigned short* Wpl = Wph + (size_t)DIMH * DIMIN;
    unsigned short* Wuh = Wpl + (size_t)DIMH * DIMIN;
    unsigned short* Wul = Wuh + (size_t)DIMH * DIMH;
    float* mm   = (float*)(Wul + (size_t)DIMH * DIMH);
    float* cval = mm + MEMN;
    float* cv2  = cval + (size_t)NROWS * CSLOTS;
    int*   cidx = (int*)(cv2 + (size_t)NROWS * CSLOTS);
    int*   cidx2 = cidx + (size_t)NROWS * CSLOTS;
    int*   bidx = cidx2 + (size_t)NROWS * CSLOTS;
    int*   list = bidx + NROWS;
    int*   count = list + NROWS;

    k_sumsq_split<<<MEMN / 4, 256, 0, stream>>>(memory, mm, Mh, Ml);
    k_split<<<(DIMH * DIMIN) / (8 * 256), 256, 0, stream>>>(W_proj, Wph, Wpl, DIMH * DIMIN);
    k_split<<<(DIMH * DIMH) / (8 * 256), 256, 0, stream>>>(W_upd, Wuh, Wul, DIMH * DIMH);
    k_proj_mfma<<<dim3(NROWS / 128, DIMH / 128), 256, 0, stream>>>(
        visual, Wph, Wpl, b_proj, Ph, Pl);
    k_argmin_mfma<<<dim3(NROWS / 128, NSPLIT), 256, 0, stream>>>(
        Ph, Pl, Mh, Ml, mm, cval, cidx, cv2, cidx2);
    hipMemsetAsync(count, 0, 4, stream);
    k_merge_gather<<<NROWS / 4, 256, 0, stream>>>(
        cval, cidx, cv2, memory, out0, bidx, count, list);
    k_rescan<<<1024, 256, 0, stream>>>(
        visual, W_proj, b_proj, memory, mm, count, list, cidx, cidx2, bidx, out0);
    hipMemcpyAsync(out1, memory, (size_t)MEMN * DIMH * 4, hipMemcpyDeviceToDevice, stream);
    k_upd_mfma<<<dim3(NROWS / 128, DIMH / 128), 256, 0, stream>>>(
        Ph, Pl, memory, bidx, Wuh, Wul, b_upd, out1);
}